// Round 7
// baseline (3913.174 us; speedup 1.0000x reference)
//
#include <hip/hip_runtime.h>
#include <stdint.h>

#define DI __device__ __forceinline__

typedef short s16x8 __attribute__((ext_vector_type(8)));
typedef float f32x4 __attribute__((ext_vector_type(4)));

// ---- constants ----
#define NG   2048
#define NP   512
#define TT   100
#define BB   256
#define N4   8192   // 4*NG
#define MR   25600  // B*T
#define NBLK 256    // persistent grid size

DI unsigned short f32_to_bf16(float f) {
  union { float f; uint32_t u; } x; x.f = f;
  uint32_t r = x.u + 0x7fffu + ((x.u >> 16) & 1u);
  return (unsigned short)(r >> 16);
}

DI void async16(const void* g, void* l) {
  __builtin_amdgcn_global_load_lds((const __attribute__((address_space(1))) void*)g,
                                   (__attribute__((address_space(3))) void*)l,
                                   16, 0, 0);
}
DI void async4(const void* g, void* l) {
  __builtin_amdgcn_global_load_lds((const __attribute__((address_space(1))) void*)g,
                                   (__attribute__((address_space(3))) void*)l,
                                   4, 0, 0);
}

DI f32x4 mfma16(s16x8 a, s16x8 b, f32x4 c) {
  return __builtin_amdgcn_mfma_f32_16x16x32_bf16(a, b, c, 0, 0, 0);
}

__global__ __launch_bounds__(256) void k_zero(unsigned* p) {
  if (threadIdx.x < 160) p[threadIdx.x] = 0u;
}

// ---- software grid barrier: monotonic counters, RELAXED agent atomics ----
// (round-4/5 proven) No fences: cross-XCD data (hs) moves via write-through
// stores (drained by vmcnt(0) before arrival) and first-touch cached reads.
DI void grid_barrier2(unsigned* bar, int xcd, int t) {
  asm volatile("s_waitcnt vmcnt(0)" ::: "memory");  // h-stores globally visible
  __syncthreads();
  if (threadIdx.x == 0) {
    unsigned a = __hip_atomic_fetch_add(bar + xcd * 16, 1u,
                                        __ATOMIC_RELAXED, __HIP_MEMORY_SCOPE_AGENT);
    if (a + 1u == 32u * (unsigned)(t + 1)) {        // last block of this XCD
      unsigned g2 = __hip_atomic_fetch_add(bar + 128, 1u,
                                           __ATOMIC_RELAXED, __HIP_MEMORY_SCOPE_AGENT);
      if (g2 + 1u == 8u * (unsigned)(t + 1))        // last XCD
        __hip_atomic_store(bar + 144, (unsigned)(t + 1),
                           __ATOMIC_RELAXED, __HIP_MEMORY_SCOPE_AGENT);
    }
    while (__hip_atomic_load(bar + 144, __ATOMIC_RELAXED,
                             __HIP_MEMORY_SCOPE_AGENT) < (unsigned)(t + 1))
      __builtin_amdgcn_s_sleep(8);
  }
  __syncthreads();
}

// =====================================================================
// Pipelined bf16 MFMA core (non-persistent kernels) — unchanged.
// =====================================================================
template <int BM>
DI void gemm_core_p(const unsigned short* __restrict__ A, int lda, int m0,
                    const unsigned short* __restrict__ Bt, int ldb, int n0, int K,
                    unsigned short* sA, unsigned short* sB, f32x4* acc) {
  constexpr int FM = BM / 32;
  const int tid  = threadIdx.x;
  const int wave = tid >> 6;
  const int lane = tid & 63;
  const int quad = lane >> 4;
  const int lr   = lane & 15;
  const int wm   = wave >> 2;
  const int wn   = wave & 3;
  const int lr8  = lane >> 3;
  const int lc8  = lane & 7;
  const int scol = (lc8 ^ lr8) << 3;

  const int nkt = K >> 6;
  int buf = 0;

  auto stage = [&](int bsel, int k0) {
    unsigned short* dA = sA + bsel * (BM * 64);
    unsigned short* dB = sB + bsel * (128 * 64);
#pragma unroll
    for (int c = 0; c < BM / 64; ++c) {
      int rbase = wave * (BM / 8) + c * 8;
      const unsigned short* g = A + (size_t)(m0 + rbase + lr8) * lda + (k0 + scol);
      async16(g, dA + rbase * 64);
    }
#pragma unroll
    for (int c = 0; c < 2; ++c) {
      int rbase = wave * 16 + c * 8;
      const unsigned short* g = Bt + (size_t)(n0 + rbase + lr8) * ldb + (k0 + scol);
      async16(g, dB + rbase * 64);
    }
  };

  stage(0, 0);
  __syncthreads();
  for (int kt = 0; kt < nkt; ++kt) {
    if (kt + 1 < nkt) stage(buf ^ 1, (kt + 1) << 6);
    const char* cA = (const char*)(sA + buf * (BM * 64));
    const char* cB = (const char*)(sB + buf * (128 * 64));
#pragma unroll
    for (int ks = 0; ks < 2; ++ks) {
      s16x8 af[FM], bfr[2];
#pragma unroll
      for (int fm = 0; fm < FM; ++fm) {
        int row = wm * (BM / 2) + fm * 16 + lr;
        int off = row * 128 + ((ks * 64 + quad * 16) ^ ((row & 7) << 4));
        af[fm] = *(const s16x8*)(cA + off);
      }
#pragma unroll
      for (int fn = 0; fn < 2; ++fn) {
        int col = wn * 32 + fn * 16 + lr;
        int off = col * 128 + ((ks * 64 + quad * 16) ^ ((col & 7) << 4));
        bfr[fn] = *(const s16x8*)(cB + off);
      }
#pragma unroll
      for (int fm = 0; fm < FM; ++fm)
#pragma unroll
        for (int fn = 0; fn < 2; ++fn)
          acc[fm * 2 + fn] = mfma16(af[fm], bfr[fn], acc[fm * 2 + fn]);
    }
    __syncthreads();
    buf ^= 1;
  }
}

// =====================================================================
// Transpose + fp32->bf16. MODE 0: n = c + noff. MODE 1 (lstm_U gate/cell
// permutation): n = ((c&2047)>>4)*64 + ((c>>11)<<4) + (c&15)  — each
// 64-col group = 16 cells x 4 gates, so one lane's acc holds all 4 gates.
// =====================================================================
template <int MODE>
__global__ __launch_bounds__(256) void k_transpose_bf16(
    const float* __restrict__ src, unsigned short* __restrict__ dst,
    int R, int C, int noff) {
  __shared__ unsigned short tile[64][65];
  int tr0 = blockIdx.x * 64;
  int tc0 = blockIdx.y * 64;
  int tid = threadIdx.x;
#pragma unroll
  for (int i = 0; i < 16; ++i) {
    int idx = tid + i * 256;
    int r = idx >> 6, c = idx & 63;
    tile[r][c] = f32_to_bf16(src[(size_t)(tr0 + r) * C + (tc0 + c)]);
  }
  __syncthreads();
#pragma unroll
  for (int i = 0; i < 16; ++i) {
    int idx = tid + i * 256;
    int cc = idx >> 6, r = idx & 63;
    int c = tc0 + cc;
    int n = (MODE == 0) ? (c + noff)
                        : ((((c & 2047) >> 4) << 6) | (((c >> 11) & 3) << 4) | (c & 15));
    dst[(size_t)n * R + (tr0 + r)] = tile[r][cc];
  }
}

__global__ __launch_bounds__(256) void k_cvt(const float* __restrict__ src,
                                             unsigned short* __restrict__ dst, int n) {
  int i = blockIdx.x * 256 + threadIdx.x;
  if (i < n) dst[i] = f32_to_bf16(src[i]);
}

// ---- W2 = M_W @ lstm_W, bias2 = M_b @ lstm_W + lstm_b (gate-permuted) ----
__global__ __launch_bounds__(256) void k_prep_xw_part(
    const float* __restrict__ lstm_W, const float* __restrict__ M_W,
    const float* __restrict__ M_b, float* __restrict__ part) {
  int c = blockIdx.x * 256 + threadIdx.x;
  int kc = blockIdx.y;
  int k0 = kc * 128;
  float a0 = 0.f, a1 = 0.f, ab = 0.f;
  for (int k = k0; k < k0 + 128; ++k) {
    float w = lstm_W[(size_t)k * N4 + c];
    a0 += M_W[k] * w;
    a1 += M_W[NG + k] * w;
    ab += M_b[k] * w;
  }
  float* p = part + (size_t)kc * 3 * N4;
  p[c] = a0; p[N4 + c] = a1; p[2 * N4 + c] = ab;
}

__global__ __launch_bounds__(256) void k_prep_xw_reduce(
    const float* __restrict__ part, const float* __restrict__ lstm_b,
    float* __restrict__ W2r, float* __restrict__ b2r) {
  int c = blockIdx.x * 256 + threadIdx.x;
  float a0 = 0.f, a1 = 0.f, ab = 0.f;
  for (int kc = 0; kc < 16; ++kc) {
    const float* p = part + (size_t)kc * 3 * N4;
    a0 += p[c]; a1 += p[N4 + c]; ab += p[2 * N4 + c];
  }
  int n = (((c & 2047) >> 4) << 6) | (((c >> 11) & 3) << 4) | (c & 15);
  W2r[n] = a0; W2r[N4 + n] = a1; b2r[n] = ab + lstm_b[c];
}

// ---- encoders: [h0 | c0] = p0 @ [enc1_W ; enc2_W] packed as N=4096 ----
__global__ __launch_bounds__(512) void k_enc(
    const unsigned short* __restrict__ p0b, const unsigned short* __restrict__ encWt,
    const float* __restrict__ enc1_b, const float* __restrict__ enc2_b,
    unsigned short* __restrict__ hbf, float* __restrict__ cfp) {
  __shared__ __align__(16) unsigned short sA[2 * 64 * 64];
  __shared__ __align__(16) unsigned short sB[2 * 128 * 64];
  int m0 = blockIdx.x * 64, n0 = blockIdx.y * 128;
  const f32x4 vzero = {0.f, 0.f, 0.f, 0.f};
  f32x4 acc[4];
#pragma unroll
  for (int i = 0; i < 4; ++i) acc[i] = vzero;
  gemm_core_p<64>(p0b, NP, m0, encWt, NP, n0, NP, sA, sB, acc);

  const int tid = threadIdx.x, wave = tid >> 6, lane = tid & 63;
  const int quad = lane >> 4, lr = lane & 15, wm = wave >> 2, wn = wave & 3;
#pragma unroll
  for (int fm = 0; fm < 2; ++fm)
#pragma unroll
    for (int fn = 0; fn < 2; ++fn)
#pragma unroll
      for (int reg = 0; reg < 4; ++reg) {
        int grow = m0 + wm * 32 + fm * 16 + quad * 4 + reg;
        int gcol = n0 + wn * 32 + fn * 16 + lr;
        float val = acc[fm * 2 + fn][reg];
        if (gcol < NG)
          hbf[(size_t)grow * NG + gcol] = f32_to_bf16(val + enc1_b[gcol]);
        else
          cfp[(size_t)grow * NG + (gcol - NG)] = val + enc2_b[gcol - NG];
      }
}

// ---- persistent recurrence: all 100 LSTM steps ----
// 256 blocks (4 mt x 64 nt, XCD swizzle), 256 threads (4 waves, 2x2 of
// 32x64 wave tiles). B (Ut) fragments loaded DIRECTLY global->register
// (16B contiguous in n-major layout; L2-resident panel) with a named
// B0/B1 register double buffer. A (h) staged via reg->swizzled-ds_write
// into a 2-slot LDS dbuf. One __syncthreads per phase (compiler-managed
// waitcnts; its barrier drain = the 1-phase prefetch distance).
// Register gate epilogue (c state in VGPRs); round-5 2-level tree barrier.
__global__ __launch_bounds__(256) void k_steps(
    const unsigned short* __restrict__ Ut,
    const float* __restrict__ vv, const float* __restrict__ W2r,
    const float* __restrict__ b2r, const float* __restrict__ cfp,
    const unsigned short* __restrict__ hb0,
    unsigned short* __restrict__ hs, unsigned* __restrict__ bar) {
  // LDS: A dbuf 2x8KB @0, vvx @16384, vvy @16640, htmp @16896 (4KB)
  __shared__ __align__(16) char smem[20992];

  const int bid = blockIdx.x;           // XCD swizzle keeps Ut panel L2-resident
  const int xcd = bid & 7, sb = bid >> 3;
  const int mt = sb >> 3, nsub = sb & 7;
  const int nt = xcd * 8 + nsub;
  const int m0 = mt * 64, n0 = nt * 128;
  const int tid = threadIdx.x;
  const int wave = tid >> 6, lane = tid & 63;
  const int quad = lane >> 4, lr = lane & 15;
  const int wm = wave >> 1, wn = wave & 1;

  // ---- t-invariant state in registers ----
  float w2x[4], w2y[4], bz[4];
#pragma unroll
  for (int g = 0; g < 4; ++g) {
    const int idx = n0 + wn * 64 + g * 16 + lr;
    w2x[g] = W2r[idx]; w2y[g] = W2r[N4 + idx]; bz[g] = b2r[idx];
    asm volatile("" : "+v"(w2x[g])); asm volatile("" : "+v"(w2y[g]));
    asm volatile("" : "+v"(bz[g]));
  }
  const int cellg = nt * 32 + wn * 16 + lr;       // this thread's cell
  float cst[2][4];
#pragma unroll
  for (int fm = 0; fm < 2; ++fm)
#pragma unroll
    for (int reg = 0; reg < 4; ++reg) {
      const int r = wm * 32 + fm * 16 + quad * 4 + reg;
      cst[fm][reg] = cfp[(size_t)(m0 + r) * NG + cellg];
      asm volatile("" : "+v"(cst[fm][reg]));
    }

  // B per-lane base pointers (t-invariant; advance 64 elems/phase, reset/step)
  const unsigned short* bB0s[4];
  const unsigned short* bB[4];
#pragma unroll
  for (int fn = 0; fn < 4; ++fn) {
    bB0s[fn] = Ut + (size_t)(n0 + wn * 64 + fn * 16 + lr) * NG + quad * 8;
    bB[fn] = bB0s[fn];
  }

  // A stage lane mapping: row ar = tid>>2, two 16B chunks per lane
  const int ar = tid >> 2;
  const int aq = tid & 3;
  const int awz = (ar & 7) << 4;
  const int awo0 = ar * 128 + ((aq * 32) ^ awz);
  const int awo1 = ar * 128 + ((aq * 32 + 16) ^ awz);

  f32x4 acc[8];

  auto loadB = [&](s16x8* d) {
#pragma unroll
    for (int fn = 0; fn < 4; ++fn) {
      d[fn * 2 + 0] = *(const s16x8*)(bB[fn]);
      d[fn * 2 + 1] = *(const s16x8*)(bB[fn] + 32);
    }
#pragma unroll
    for (int fn = 0; fn < 4; ++fn) bB[fn] += 64;
  };

  auto computeS = [&](int slot, const s16x8* B) {
    const char* cA = smem + slot * 8192;
#pragma unroll
    for (int ks = 0; ks < 2; ++ks) {
      s16x8 af[2];
#pragma unroll
      for (int fm = 0; fm < 2; ++fm) {
        const int row = wm * 32 + fm * 16 + lr;
        af[fm] = *(const s16x8*)(cA + row * 128 + ((ks * 64 + quad * 16) ^ ((row & 7) << 4)));
      }
#pragma unroll
      for (int fm = 0; fm < 2; ++fm)
#pragma unroll
        for (int fn = 0; fn < 4; ++fn)
          acc[fm * 4 + fn] = mfma16(af[fm], B[fn * 2 + ks], acc[fm * 4 + fn]);
    }
  };

  // phase: ds_write A(k_{p+1})->slot^1, issue B(k_{p+1})->Bn, issue A(k_{p+2})->Ald,
  //        compute slot with Bc, barrier.
  auto phaseF = [&](int slot, const s16x8* Bc, s16x8* Bn,
                    const s16x8* Awr, s16x8* Ald, const unsigned short* aG) {
    if (Awr) {
      char* d = smem + ((slot ^ 1) * 8192);
      *(s16x8*)(d + awo0) = Awr[0];
      *(s16x8*)(d + awo1) = Awr[1];
    }
    loadB(Bn);
    if (aG) { Ald[0] = *(const s16x8*)aG; Ald[1] = *(const s16x8*)(aG + 8); }
    computeS(slot, Bc);
    __syncthreads();
  };

  s16x8 B0[8], B1[8], Aw[2], Ax[2];
  loadB(B0);                                   // k0 of step 0 (bB -> k64)

  for (int t = 0; t < TT; ++t) {
    const unsigned short* hin = t ? hs + (size_t)(t - 1) * BB * NG : hb0;
    const unsigned short* aB = hin + (size_t)(m0 + ar) * NG + aq * 16;
    // stage v_t (all waves duplicate same dest; benign)
    { const float* gx = vv + ((size_t)(m0 + lane) * TT + t) * 2;
      async4(gx, smem + 16384); async4(gx + 1, smem + 16640); }

    // prologue: A(k0) -> slot0; A(k1) -> Ax
    Aw[0] = *(const s16x8*)(aB); Aw[1] = *(const s16x8*)(aB + 8);
    { char* d = smem;
      *(s16x8*)(d + awo0) = Aw[0]; *(s16x8*)(d + awo1) = Aw[1]; }
    Ax[0] = *(const s16x8*)(aB + 64); Ax[1] = *(const s16x8*)(aB + 64 + 8);
    const f32x4 vzero = {0.f, 0.f, 0.f, 0.f};
#pragma unroll
    for (int i = 0; i < 8; ++i) acc[i] = vzero;
    __syncthreads();

    // phases 0..29 (pairs); even p: slot0/B0, odd p: slot1/B1
    int ao = 128;                              // elem offset of k_{p+2}
    for (int pp = 0; pp < 15; ++pp) {
      phaseF(0, B0, B1, Ax, Aw, aB + ao); ao += 64;
      phaseF(1, B1, B0, Aw, Ax, aB + ao); ao += 64;
    }
    // phase 30: write A(k31), load B(k31), no A-load
    phaseF(0, B0, B1, Ax, Aw, nullptr);
    // phase 31: no A-write; reset B pointers and prefetch next step's B(k0)
#pragma unroll
    for (int fn = 0; fn < 4; ++fn) bB[fn] = bB0s[fn];
    phaseF(1, B1, B0, nullptr, Ax, nullptr);

    // ---- register gate epilogue ----
    const float* vx = (const float*)(smem + 16384);
    const float* vy = (const float*)(smem + 16640);
    unsigned short* htmp = (unsigned short*)(smem + 16896);
#pragma unroll
    for (int fm = 0; fm < 2; ++fm)
#pragma unroll
      for (int reg = 0; reg < 4; ++reg) {
        const int r = wm * 32 + fm * 16 + quad * 4 + reg;
        const float ax = vx[r], ay = vy[r];
        float zi = acc[fm * 4 + 0][reg] + ax * w2x[0] + ay * w2y[0] + bz[0];
        float zf = acc[fm * 4 + 1][reg] + ax * w2x[1] + ay * w2y[1] + bz[1];
        float zg = acc[fm * 4 + 2][reg] + ax * w2x[2] + ay * w2y[2] + bz[2];
        float zo = acc[fm * 4 + 3][reg] + ax * w2x[3] + ay * w2y[3] + bz[3];
        float i_ = 1.f / (1.f + __expf(-zi));
        float f_ = 1.f / (1.f + __expf(-zf));
        float g_ = fmaxf(zg, 0.f);
        float o_ = 1.f / (1.f + __expf(-zo));
        float cn = f_ * cst[fm][reg] + i_ * g_;
        cst[fm][reg] = cn;
        htmp[r * 32 + wn * 16 + lr] = f32_to_bf16(o_ * fmaxf(cn, 0.f));
      }
    __syncthreads();
    // coalesced 4B write-through h stores into hs[t]
    const unsigned* hw = (const unsigned*)htmp;
#pragma unroll
    for (int p = 0; p < 4; ++p) {
      const int q = tid + p * 256;       // 0..1023 uints (64 rows x 16)
      const int r = q >> 4, cq = q & 15;
      unsigned* hp = (unsigned*)(hs + ((size_t)t * BB + m0 + r) * NG) + (nt * 16 + cq);
      __hip_atomic_store(hp, hw[q], __ATOMIC_RELAXED, __HIP_MEMORY_SCOPE_AGENT);
    }
    if (t + 1 < TT) grid_barrier2(bar, xcd, t);
  }
}

// ---- g_cells = relu(hs @ dense_W + dense_b) -> bf16 ----
__global__ __launch_bounds__(512) void k_dense(
    const unsigned short* __restrict__ hs, const unsigned short* __restrict__ dWt,
    const float* __restrict__ dense_b, unsigned short* __restrict__ gc) {
  __shared__ __align__(16) unsigned short sA[2 * 128 * 64];
  __shared__ __align__(16) unsigned short sB[2 * 128 * 64];
  int bid = blockIdx.x;
  int mt = bid >> 4;
  int r4 = bid & 15;
  int nt = ((r4 & 7) << 1) | (r4 >> 3);   // fixed nt pair per XCD
  int m0 = mt * 128, n0 = nt * 128;
  const f32x4 vzero = {0.f, 0.f, 0.f, 0.f};
  f32x4 acc[8];
#pragma unroll
  for (int i = 0; i < 8; ++i) acc[i] = vzero;
  gemm_core_p<128>(hs, NG, m0, dWt, NG, n0, NG, sA, sB, acc);

  const int tid = threadIdx.x, wave = tid >> 6, lane = tid & 63;
  const int quad = lane >> 4, lr = lane & 15, wm = wave >> 2, wn = wave & 3;
#pragma unroll
  for (int fm = 0; fm < 4; ++fm)
#pragma unroll
    for (int fn = 0; fn < 2; ++fn)
#pragma unroll
      for (int reg = 0; reg < 4; ++reg) {
        int grow = m0 + wm * 64 + fm * 16 + quad * 4 + reg;
        int gcol = n0 + wn * 32 + fn * 16 + lr;
        float val = fmaxf(acc[fm * 2 + fn][reg] + dense_b[gcol], 0.f);
        gc[(size_t)grow * NG + gcol] = f32_to_bf16(val);
      }
}

// ---- place_preds = g_cells @ dec_W + dec_b (fp32 out, [B][T][Np]) ----
__global__ __launch_bounds__(512) void k_dec(
    const unsigned short* __restrict__ gc, const unsigned short* __restrict__ decWt,
    const float* __restrict__ dec_b, float* __restrict__ out) {
  __shared__ __align__(16) unsigned short sA[2 * 128 * 64];
  __shared__ __align__(16) unsigned short sB[2 * 128 * 64];
  int m0 = blockIdx.x * 128, n0 = blockIdx.y * 128;
  const f32x4 vzero = {0.f, 0.f, 0.f, 0.f};
  f32x4 acc[8];
#pragma unroll
  for (int i = 0; i < 8; ++i) acc[i] = vzero;
  gemm_core_p<128>(gc, NG, m0, decWt, NG, n0, NG, sA, sB, acc);

  const int tid = threadIdx.x, wave = tid >> 6, lane = tid & 63;
  const int quad = lane >> 4, lr = lane & 15, wm = wave >> 2, wn = wave & 3;
#pragma unroll
  for (int fm = 0; fm < 4; ++fm)
#pragma unroll
    for (int fn = 0; fn < 2; ++fn)
#pragma unroll
      for (int reg = 0; reg < 4; ++reg) {
        int grow = m0 + wm * 64 + fm * 16 + quad * 4 + reg;   // t*256+b
        int gcol = n0 + wn * 32 + fn * 16 + lr;               // 0..511
        int tt = grow >> 8, b = grow & 255;
        out[((size_t)b * TT + tt) * NP + gcol] = acc[fm * 2 + fn][reg] + dec_b[gcol];
      }
}

// =====================================================================
extern "C" void kernel_launch(void* const* d_in, const int* in_sizes, int n_in,
                              void* d_out, int out_size, void* d_ws, size_t ws_size,
                              hipStream_t stream) {
  (void)in_sizes; (void)n_in; (void)out_size; (void)ws_size;
  const float* v       = (const float*)d_in[0];
  const float* p0      = (const float*)d_in[1];
  const float* enc1_W  = (const float*)d_in[2];
  const float* enc1_b  = (const float*)d_in[3];
  const float* enc2_W  = (const float*)d_in[4];
  const float* enc2_b  = (const float*)d_in[5];
  const float* M_W     = (const float*)d_in[6];
  const float* M_b     = (const float*)d_in[7];
  const float* lstm_W  = (const float*)d_in[8];
  const float* lstm_U  = (const float*)d_in[9];
  const float* lstm_b  = (const float*)d_in[10];
  const float* dense_W = (const float*)d_in[11];
  const float* dense_b = (const float*)d_in[12];
  const float* dec_W   = (const float*)d_in[13];
  const float* dec_b   = (const float*)d_in[14];
  float* out = (float*)d_out;

  char* ws = (char*)d_ws;
  size_t off = 0;
  auto alloc = [&](size_t bytes) {
    char* p = ws + off;
    off += (bytes + 255) & ~(size_t)255;
    return p;
  };
  unsigned short* Ut    = (unsigned short*)alloc((size_t)N4 * NG * 2);   // 32 MB
  unsigned short* dWt   = (unsigned short*)alloc((size_t)NG * NG * 2);   // 8 MB
  unsigned short* decWt = (unsigned short*)alloc((size_t)NP * NG * 2);   // 2 MB
  unsigned short* encWt = (unsigned short*)alloc((size_t)2 * NG * NP * 2);
  unsigned short* p0b   = (unsigned short*)alloc((size_t)BB * NP * 2);
  float* W2r  = (float*)alloc((size_t)2 * N4 * 4);
  float* b2r  = (float*)alloc((size_t)N4 * 4);
  float* part = (float*)alloc((size_t)16 * 3 * N4 * 4);
  float* cfp  = (float*)alloc((size_t)BB * NG * 4);
  unsigned short* hb0 = (unsigned short*)alloc((size_t)BB * NG * 2);
  unsigned short* hs  = (unsigned short*)alloc((size_t)MR * NG * 2);     // 100 MB
  unsigned short* gc  = (unsigned short*)alloc((size_t)MR * NG * 2);     // 100 MB
  unsigned* bar = (unsigned*)alloc(1024);                                // barrier words

  dim3 blk(256), blk5(512);
  // barrier init (fresh every launch/replay)
  k_zero<<<dim3(1), blk, 0, stream>>>(bar);
  // weight conversion / transposes
  k_transpose_bf16<1><<<dim3(32, 128), blk, 0, stream>>>(lstm_U, Ut, NG, N4, 0);
  k_transpose_bf16<0><<<dim3(32, 32), blk, 0, stream>>>(dense_W, dWt, NG, NG, 0);
  k_transpose_bf16<0><<<dim3(32, 8), blk, 0, stream>>>(dec_W, decWt, NG, NP, 0);
  k_transpose_bf16<0><<<dim3(8, 32), blk, 0, stream>>>(enc1_W, encWt, NP, NG, 0);
  k_transpose_bf16<0><<<dim3(8, 32), blk, 0, stream>>>(enc2_W, encWt, NP, NG, NG);
  k_cvt<<<dim3(512), blk, 0, stream>>>(p0, p0b, BB * NP);
  // rank-2 collapse of input path
  k_prep_xw_part<<<dim3(32, 16), blk, 0, stream>>>(lstm_W, M_W, M_b, part);
  k_prep_xw_reduce<<<dim3(32), blk, 0, stream>>>(part, lstm_b, W2r, b2r);
  // initial state
  k_enc<<<dim3(4, 32), blk5, 0, stream>>>(p0b, encWt, enc1_b, enc2_b, hb0, cfp);
  // recurrence: one persistent kernel, 100 steps
  k_steps<<<dim3(NBLK), blk, 0, stream>>>(Ut, v, W2r, b2r, cfp, hb0, hs, bar);
  // readout
  k_dense<<<dim3(3200), blk5, 0, stream>>>(hs, dWt, dense_b, gc);
  k_dec<<<dim3(200, 4), blk5, 0, stream>>>(gc, decWt, dec_b, out);
}

// Round 8
// 2089.849 us; speedup vs baseline: 1.8725x; 1.8725x over previous
//
#include <hip/hip_runtime.h>
#include <stdint.h>

#define DI __device__ __forceinline__

typedef short s16x8 __attribute__((ext_vector_type(8)));
typedef float f32x4 __attribute__((ext_vector_type(4)));

// ---- constants ----
#define NG   2048
#define NP   512
#define TT   100
#define BB   256
#define N4   8192   // 4*NG
#define MR   25600  // B*T
#define NBLK 256    // persistent grid size

DI unsigned short f32_to_bf16(float f) {
  union { float f; uint32_t u; } x; x.f = f;
  uint32_t r = x.u + 0x7fffu + ((x.u >> 16) & 1u);
  return (unsigned short)(r >> 16);
}

DI void async16(const void* g, void* l) {
  __builtin_amdgcn_global_load_lds((const __attribute__((address_space(1))) void*)g,
                                   (__attribute__((address_space(3))) void*)l,
                                   16, 0, 0);
}
DI void async4(const void* g, void* l) {
  __builtin_amdgcn_global_load_lds((const __attribute__((address_space(1))) void*)g,
                                   (__attribute__((address_space(3))) void*)l,
                                   4, 0, 0);
}

DI f32x4 mfma16(s16x8 a, s16x8 b, f32x4 c) {
  return __builtin_amdgcn_mfma_f32_16x16x32_bf16(a, b, c, 0, 0, 0);
}

__global__ __launch_bounds__(256) void k_zero(unsigned* p) {
  if (threadIdx.x < 160) p[threadIdx.x] = 0u;
}

// ---- software grid barrier: monotonic counters, RELAXED agent atomics ----
// (round-4/5 proven) No fences: cross-XCD data (hs) moves via write-through
// stores (drained by vmcnt(0) before arrival) and first-touch cached reads.
DI void grid_barrier2(unsigned* bar, int xcd, int t) {
  asm volatile("s_waitcnt vmcnt(0)" ::: "memory");  // h-stores globally visible
  __syncthreads();
  if (threadIdx.x == 0) {
    unsigned a = __hip_atomic_fetch_add(bar + xcd * 16, 1u,
                                        __ATOMIC_RELAXED, __HIP_MEMORY_SCOPE_AGENT);
    if (a + 1u == 32u * (unsigned)(t + 1)) {        // last block of this XCD
      unsigned g2 = __hip_atomic_fetch_add(bar + 128, 1u,
                                           __ATOMIC_RELAXED, __HIP_MEMORY_SCOPE_AGENT);
      if (g2 + 1u == 8u * (unsigned)(t + 1))        // last XCD
        __hip_atomic_store(bar + 144, (unsigned)(t + 1),
                           __ATOMIC_RELAXED, __HIP_MEMORY_SCOPE_AGENT);
    }
    while (__hip_atomic_load(bar + 144, __ATOMIC_RELAXED,
                             __HIP_MEMORY_SCOPE_AGENT) < (unsigned)(t + 1))
      __builtin_amdgcn_s_sleep(8);
  }
  __syncthreads();
}

// =====================================================================
// Pipelined bf16 MFMA core (non-persistent kernels) — unchanged.
// =====================================================================
template <int BM>
DI void gemm_core_p(const unsigned short* __restrict__ A, int lda, int m0,
                    const unsigned short* __restrict__ Bt, int ldb, int n0, int K,
                    unsigned short* sA, unsigned short* sB, f32x4* acc) {
  constexpr int FM = BM / 32;
  const int tid  = threadIdx.x;
  const int wave = tid >> 6;
  const int lane = tid & 63;
  const int quad = lane >> 4;
  const int lr   = lane & 15;
  const int wm   = wave >> 2;
  const int wn   = wave & 3;
  const int lr8  = lane >> 3;
  const int lc8  = lane & 7;
  const int scol = (lc8 ^ lr8) << 3;

  const int nkt = K >> 6;
  int buf = 0;

  auto stage = [&](int bsel, int k0) {
    unsigned short* dA = sA + bsel * (BM * 64);
    unsigned short* dB = sB + bsel * (128 * 64);
#pragma unroll
    for (int c = 0; c < BM / 64; ++c) {
      int rbase = wave * (BM / 8) + c * 8;
      const unsigned short* g = A + (size_t)(m0 + rbase + lr8) * lda + (k0 + scol);
      async16(g, dA + rbase * 64);
    }
#pragma unroll
    for (int c = 0; c < 2; ++c) {
      int rbase = wave * 16 + c * 8;
      const unsigned short* g = Bt + (size_t)(n0 + rbase + lr8) * ldb + (k0 + scol);
      async16(g, dB + rbase * 64);
    }
  };

  stage(0, 0);
  __syncthreads();
  for (int kt = 0; kt < nkt; ++kt) {
    if (kt + 1 < nkt) stage(buf ^ 1, (kt + 1) << 6);
    const char* cA = (const char*)(sA + buf * (BM * 64));
    const char* cB = (const char*)(sB + buf * (128 * 64));
#pragma unroll
    for (int ks = 0; ks < 2; ++ks) {
      s16x8 af[FM], bfr[2];
#pragma unroll
      for (int fm = 0; fm < FM; ++fm) {
        int row = wm * (BM / 2) + fm * 16 + lr;
        int off = row * 128 + ((ks * 64 + quad * 16) ^ ((row & 7) << 4));
        af[fm] = *(const s16x8*)(cA + off);
      }
#pragma unroll
      for (int fn = 0; fn < 2; ++fn) {
        int col = wn * 32 + fn * 16 + lr;
        int off = col * 128 + ((ks * 64 + quad * 16) ^ ((col & 7) << 4));
        bfr[fn] = *(const s16x8*)(cB + off);
      }
#pragma unroll
      for (int fm = 0; fm < FM; ++fm)
#pragma unroll
        for (int fn = 0; fn < 2; ++fn)
          acc[fm * 2 + fn] = mfma16(af[fm], bfr[fn], acc[fm * 2 + fn]);
    }
    __syncthreads();
    buf ^= 1;
  }
}

// =====================================================================
// Transpose + fp32->bf16. MODE 0: n = c + noff. MODE 1 (lstm_U gate/cell
// permutation): n = ((c&2047)>>4)*64 + ((c>>11)<<4) + (c&15)  — each
// 64-col group = 16 cells x 4 gates, so one lane's acc holds all 4 gates.
// =====================================================================
template <int MODE>
__global__ __launch_bounds__(256) void k_transpose_bf16(
    const float* __restrict__ src, unsigned short* __restrict__ dst,
    int R, int C, int noff) {
  __shared__ unsigned short tile[64][65];
  int tr0 = blockIdx.x * 64;
  int tc0 = blockIdx.y * 64;
  int tid = threadIdx.x;
#pragma unroll
  for (int i = 0; i < 16; ++i) {
    int idx = tid + i * 256;
    int r = idx >> 6, c = idx & 63;
    tile[r][c] = f32_to_bf16(src[(size_t)(tr0 + r) * C + (tc0 + c)]);
  }
  __syncthreads();
#pragma unroll
  for (int i = 0; i < 16; ++i) {
    int idx = tid + i * 256;
    int cc = idx >> 6, r = idx & 63;
    int c = tc0 + cc;
    int n = (MODE == 0) ? (c + noff)
                        : ((((c & 2047) >> 4) << 6) | (((c >> 11) & 3) << 4) | (c & 15));
    dst[(size_t)n * R + (tr0 + r)] = tile[r][cc];
  }
}

__global__ __launch_bounds__(256) void k_cvt(const float* __restrict__ src,
                                             unsigned short* __restrict__ dst, int n) {
  int i = blockIdx.x * 256 + threadIdx.x;
  if (i < n) dst[i] = f32_to_bf16(src[i]);
}

// ---- W2 = M_W @ lstm_W, bias2 = M_b @ lstm_W + lstm_b (gate-permuted) ----
__global__ __launch_bounds__(256) void k_prep_xw_part(
    const float* __restrict__ lstm_W, const float* __restrict__ M_W,
    const float* __restrict__ M_b, float* __restrict__ part) {
  int c = blockIdx.x * 256 + threadIdx.x;
  int kc = blockIdx.y;
  int k0 = kc * 128;
  float a0 = 0.f, a1 = 0.f, ab = 0.f;
  for (int k = k0; k < k0 + 128; ++k) {
    float w = lstm_W[(size_t)k * N4 + c];
    a0 += M_W[k] * w;
    a1 += M_W[NG + k] * w;
    ab += M_b[k] * w;
  }
  float* p = part + (size_t)kc * 3 * N4;
  p[c] = a0; p[N4 + c] = a1; p[2 * N4 + c] = ab;
}

__global__ __launch_bounds__(256) void k_prep_xw_reduce(
    const float* __restrict__ part, const float* __restrict__ lstm_b,
    float* __restrict__ W2r, float* __restrict__ b2r) {
  int c = blockIdx.x * 256 + threadIdx.x;
  float a0 = 0.f, a1 = 0.f, ab = 0.f;
  for (int kc = 0; kc < 16; ++kc) {
    const float* p = part + (size_t)kc * 3 * N4;
    a0 += p[c]; a1 += p[N4 + c]; ab += p[2 * N4 + c];
  }
  int n = (((c & 2047) >> 4) << 6) | (((c >> 11) & 3) << 4) | (c & 15);
  W2r[n] = a0; W2r[N4 + n] = a1; b2r[n] = ab + lstm_b[c];
}

// ---- encoders: [h0 | c0] = p0 @ [enc1_W ; enc2_W] packed as N=4096 ----
__global__ __launch_bounds__(512) void k_enc(
    const unsigned short* __restrict__ p0b, const unsigned short* __restrict__ encWt,
    const float* __restrict__ enc1_b, const float* __restrict__ enc2_b,
    unsigned short* __restrict__ hbf, float* __restrict__ cfp) {
  __shared__ __align__(16) unsigned short sA[2 * 64 * 64];
  __shared__ __align__(16) unsigned short sB[2 * 128 * 64];
  int m0 = blockIdx.x * 64, n0 = blockIdx.y * 128;
  const f32x4 vzero = {0.f, 0.f, 0.f, 0.f};
  f32x4 acc[4];
#pragma unroll
  for (int i = 0; i < 4; ++i) acc[i] = vzero;
  gemm_core_p<64>(p0b, NP, m0, encWt, NP, n0, NP, sA, sB, acc);

  const int tid = threadIdx.x, wave = tid >> 6, lane = tid & 63;
  const int quad = lane >> 4, lr = lane & 15, wm = wave >> 2, wn = wave & 3;
#pragma unroll
  for (int fm = 0; fm < 2; ++fm)
#pragma unroll
    for (int fn = 0; fn < 2; ++fn)
#pragma unroll
      for (int reg = 0; reg < 4; ++reg) {
        int grow = m0 + wm * 32 + fm * 16 + quad * 4 + reg;
        int gcol = n0 + wn * 32 + fn * 16 + lr;
        float val = acc[fm * 2 + fn][reg];
        if (gcol < NG)
          hbf[(size_t)grow * NG + gcol] = f32_to_bf16(val + enc1_b[gcol]);
        else
          cfp[(size_t)grow * NG + (gcol - NG)] = val + enc2_b[gcol - NG];
      }
}

// ---- persistent recurrence: all 100 LSTM steps ----
// 256 blocks (4 mt x 64 nt, XCD swizzle), 512 threads = 8 waves (2/SIMD).
// K-SPLIT waves: wave (kh, wm, wn) computes the ks=kh half of each BK=64
// phase for output tile (wm*32 rows, wn*64 cols). Same LDS traffic as the
// 4-wave version, double the TLP (hides ds_read latency + barrier restart).
// Ring-5 LDS, per-phase barrier + counted vmcnt (uniform 3 ops/wave/phase),
// acc pair-merge via LDS at step end, register gate epilogue on kh=0 waves.
__global__ __launch_bounds__(512) void k_steps(
    const unsigned short* __restrict__ Ut,
    const float* __restrict__ vv, const float* __restrict__ W2r,
    const float* __restrict__ b2r, const float* __restrict__ cfp,
    const unsigned short* __restrict__ hb0,
    unsigned short* __restrict__ hs, unsigned* __restrict__ bar) {
  // A ring5 @0 (5x8KB), B ring5 @40960 (5x16KB), vvx @122880, vvy @123136,
  // htmp @123392 (4KB) -> 127488 B
  __shared__ __align__(16) char smem[127488];

  const int bid = blockIdx.x;           // XCD swizzle keeps Ut panel L2-resident
  const int xcd = bid & 7, sb = bid >> 3;
  const int mt = sb >> 3, nsub = sb & 7;
  const int nt = xcd * 8 + nsub;
  const int m0 = mt * 64, n0 = nt * 128;
  const int tid = threadIdx.x;
  const int w = tid >> 6, lane = tid & 63;
  const int kh = w >> 2;                // K-half this wave accumulates
  const int wq = w & 3;
  const int wm = wq >> 1, wn = wq & 1;
  const int quad = lane >> 4, lr = lane & 15;
  const int lr8 = lane >> 3, lc8 = lane & 7;
  const int scol = (lc8 ^ lr8) << 3;

  // ---- t-invariant state in registers (used by kh=0 waves) ----
  float w2x[4], w2y[4], bz[4];
#pragma unroll
  for (int g = 0; g < 4; ++g) {
    const int idx = n0 + wn * 64 + g * 16 + lr;
    w2x[g] = W2r[idx]; w2y[g] = W2r[N4 + idx]; bz[g] = b2r[idx];
  }
  const int cellg = nt * 32 + wn * 16 + lr;       // this thread's cell
  float cst[2][4];
#pragma unroll
  for (int fm = 0; fm < 2; ++fm)
#pragma unroll
    for (int reg = 0; reg < 4; ++reg) {
      const int r = wm * 32 + fm * 16 + quad * 4 + reg;
      cst[fm][reg] = cfp[(size_t)(m0 + r) * NG + cellg];
    }

  // staging split: per phase each wave does 1 A-op (rows 8w..8w+8) and
  // 2 B-ops (rows 16w..16w+16) -> uniform 3 vmem ops/wave/phase.
  const unsigned short* bwB = Ut + (size_t)(n0 + w * 16 + lr8) * NG + scol;
  auto stageB = [&](int slot, int k) {            // 2 ops
    char* dB = smem + 40960 + slot * 16384 + (w * 16) * 128;
    async16(bwB + k, dB);
    async16(bwB + (size_t)8 * NG + k, dB + 1024);
  };
  auto stageV = [&](int t) {                      // 2 ops (all waves duplicate)
    const float* gx = vv + ((size_t)(m0 + lane) * TT + t) * 2;
    async4(gx, smem + 122880);
    async4(gx + 1, smem + 123136);
  };

  f32x4 acc[8];
  auto computeS = [&](int slot) {
    const char* cA = smem + slot * 8192;
    const char* cB = smem + 40960 + slot * 16384;
    s16x8 af[2];
#pragma unroll
    for (int fm = 0; fm < 2; ++fm) {
      const int row = wm * 32 + fm * 16 + lr;
      af[fm] = *(const s16x8*)(cA + row * 128 + ((kh * 64 + quad * 16) ^ ((row & 7) << 4)));
    }
#pragma unroll
    for (int fn = 0; fn < 4; ++fn) {
      const int col = wn * 64 + fn * 16 + lr;
      s16x8 bf = *(const s16x8*)(cB + col * 128 + ((kh * 64 + quad * 16) ^ ((col & 7) << 4)));
#pragma unroll
      for (int fm = 0; fm < 2; ++fm)
        acc[fm * 4 + fn] = mfma16(af[fm], bf, acc[fm * 4 + fn]);
    }
  };

#define INC5(x) x = ((x) == 4) ? 0 : ((x) + 1)
#define PHASE(W)  asm volatile("s_waitcnt vmcnt(" #W ")\n\ts_barrier" ::: "memory"); \
                  computeS(cs); INC5(cs);

  asm volatile("s_waitcnt vmcnt(0)" ::: "memory");  // exact counting baseline
  int cs = 0;
  stageB(0, 0); stageB(1, 64); stageB(2, 128);      // t=0 B prefetch (6 ops, drained below? no — counted in t=0 ramp)

  for (int t = 0; t < TT; ++t) {
    const unsigned short* hin = t ? hs + (size_t)(t - 1) * BB * NG : hb0;
    const unsigned short* awA = hin + (size_t)(m0 + w * 8 + lr8) * NG + scol;
    auto stageA = [&](int slot, int kt) {         // 1 op
      async16(awA + kt * 64, smem + slot * 8192 + (w * 8) * 128);
    };

    // entry: V (2 ops) + A into slots cs..cs+2 (1 op each)
    stageV(t);
    { int s1 = cs; stageA(s1, 0); INC5(s1); stageA(s1, 1); INC5(s1); stageA(s1, 2); }
    const f32x4 vzero = {0.f, 0.f, 0.f, 0.f};
#pragma unroll
    for (int i = 0; i < 8; ++i) acc[i] = vzero;

    int ss = cs; INC5(ss); INC5(ss); INC5(ss);    // stage slot = cs+3
    stageB(ss, 3 << 6); stageA(ss, 3); INC5(ss);
    PHASE(5)
    stageB(ss, 4 << 6); stageA(ss, 4); INC5(ss);
    PHASE(7)
    stageB(ss, 5 << 6); stageA(ss, 5); INC5(ss);
    PHASE(9)
    for (int p = 3; p <= 28; ++p) {
      stageB(ss, (p + 3) << 6); stageA(ss, p + 3); INC5(ss);
      PHASE(9)
    }
    PHASE(6)
    PHASE(3)
    PHASE(0)
    // next-step B prefetch into (new) cs..cs+2 (drained by grid barrier)
    if (t + 1 < TT) {
      int s2 = cs; stageB(s2, 0); INC5(s2); stageB(s2, 64); INC5(s2); stageB(s2, 128);
    }
    __syncthreads();                 // all compute done before LDS reuse

    // ---- acc pair-merge (kh=1 -> LDS -> kh=0) ----
    if (kh) {
      f32x4* px = (f32x4*)(smem + wq * 8192 + lane * 128);
#pragma unroll
      for (int i = 0; i < 8; ++i) px[i] = acc[i];
    }
    __syncthreads();
    if (!kh) {
      const f32x4* px = (const f32x4*)(smem + wq * 8192 + lane * 128);
#pragma unroll
      for (int i = 0; i < 8; ++i) acc[i] += px[i];

      // ---- register gate epilogue ----
      const float* vx = (const float*)(smem + 122880);
      const float* vy = (const float*)(smem + 123136);
      unsigned short* htmp = (unsigned short*)(smem + 123392);
#pragma unroll
      for (int fm = 0; fm < 2; ++fm)
#pragma unroll
        for (int reg = 0; reg < 4; ++reg) {
          const int r = wm * 32 + fm * 16 + quad * 4 + reg;
          const float ax = vx[r], ay = vy[r];
          float zi = acc[fm * 4 + 0][reg] + ax * w2x[0] + ay * w2y[0] + bz[0];
          float zf = acc[fm * 4 + 1][reg] + ax * w2x[1] + ay * w2y[1] + bz[1];
          float zg = acc[fm * 4 + 2][reg] + ax * w2x[2] + ay * w2y[2] + bz[2];
          float zo = acc[fm * 4 + 3][reg] + ax * w2x[3] + ay * w2y[3] + bz[3];
          float i_ = 1.f / (1.f + __expf(-zi));
          float f_ = 1.f / (1.f + __expf(-zf));
          float g_ = fmaxf(zg, 0.f);
          float o_ = 1.f / (1.f + __expf(-zo));
          float cn = f_ * cst[fm][reg] + i_ * g_;
          cst[fm][reg] = cn;
          htmp[r * 32 + wn * 16 + lr] = f32_to_bf16(o_ * fmaxf(cn, 0.f));
        }
    }
    __syncthreads();
    // coalesced 4B write-through h stores into hs[t] (first 4 waves)
    if (tid < 256) {
      const unsigned* hw = (const unsigned*)(smem + 123392);
#pragma unroll
      for (int p = 0; p < 4; ++p) {
        const int q = tid + p * 256;       // 0..1023 uints (64 rows x 16)
        const int r = q >> 4, cq = q & 15;
        unsigned* hp = (unsigned*)(hs + ((size_t)t * BB + m0 + r) * NG) + (nt * 16 + cq);
        __hip_atomic_store(hp, hw[q], __ATOMIC_RELAXED, __HIP_MEMORY_SCOPE_AGENT);
      }
    }
    if (t + 1 < TT) grid_barrier2(bar, xcd, t);   // drains everything (vmcnt 0)
  }
#undef PHASE
#undef INC5
}

// ---- g_cells = relu(hs @ dense_W + dense_b) -> bf16 ----
__global__ __launch_bounds__(512) void k_dense(
    const unsigned short* __restrict__ hs, const unsigned short* __restrict__ dWt,
    const float* __restrict__ dense_b, unsigned short* __restrict__ gc) {
  __shared__ __align__(16) unsigned short sA[2 * 128 * 64];
  __shared__ __align__(16) unsigned short sB[2 * 128 * 64];
  int bid = blockIdx.x;
  int mt = bid >> 4;
  int r4 = bid & 15;
  int nt = ((r4 & 7) << 1) | (r4 >> 3);   // fixed nt pair per XCD
  int m0 = mt * 128, n0 = nt * 128;
  const f32x4 vzero = {0.f, 0.f, 0.f, 0.f};
  f32x4 acc[8];
#pragma unroll
  for (int i = 0; i < 8; ++i) acc[i] = vzero;
  gemm_core_p<128>(hs, NG, m0, dWt, NG, n0, NG, sA, sB, acc);

  const int tid = threadIdx.x, wave = tid >> 6, lane = tid & 63;
  const int quad = lane >> 4, lr = lane & 15, wm = wave >> 2, wn = wave & 3;
#pragma unroll
  for (int fm = 0; fm < 4; ++fm)
#pragma unroll
    for (int fn = 0; fn < 2; ++fn)
#pragma unroll
      for (int reg = 0; reg < 4; ++reg) {
        int grow = m0 + wm * 64 + fm * 16 + quad * 4 + reg;
        int gcol = n0 + wn * 32 + fn * 16 + lr;
        float val = fmaxf(acc[fm * 2 + fn][reg] + dense_b[gcol], 0.f);
        gc[(size_t)grow * NG + gcol] = f32_to_bf16(val);
      }
}

// ---- place_preds = g_cells @ dec_W + dec_b (fp32 out, [B][T][Np]) ----
__global__ __launch_bounds__(512) void k_dec(
    const unsigned short* __restrict__ gc, const unsigned short* __restrict__ decWt,
    const float* __restrict__ dec_b, float* __restrict__ out) {
  __shared__ __align__(16) unsigned short sA[2 * 128 * 64];
  __shared__ __align__(16) unsigned short sB[2 * 128 * 64];
  int m0 = blockIdx.x * 128, n0 = blockIdx.y * 128;
  const f32x4 vzero = {0.f, 0.f, 0.f, 0.f};
  f32x4 acc[8];
#pragma unroll
  for (int i = 0; i < 8; ++i) acc[i] = vzero;
  gemm_core_p<128>(gc, NG, m0, decWt, NG, n0, NG, sA, sB, acc);

  const int tid = threadIdx.x, wave = tid >> 6, lane = tid & 63;
  const int quad = lane >> 4, lr = lane & 15, wm = wave >> 2, wn = wave & 3;
#pragma unroll
  for (int fm = 0; fm < 4; ++fm)
#pragma unroll
    for (int fn = 0; fn < 2; ++fn)
#pragma unroll
      for (int reg = 0; reg < 4; ++reg) {
        int grow = m0 + wm * 64 + fm * 16 + quad * 4 + reg;   // t*256+b
        int gcol = n0 + wn * 32 + fn * 16 + lr;               // 0..511
        int tt = grow >> 8, b = grow & 255;
        out[((size_t)b * TT + tt) * NP + gcol] = acc[fm * 2 + fn][reg] + dec_b[gcol];
      }
}

// =====================================================================
extern "C" void kernel_launch(void* const* d_in, const int* in_sizes, int n_in,
                              void* d_out, int out_size, void* d_ws, size_t ws_size,
                              hipStream_t stream) {
  (void)in_sizes; (void)n_in; (void)out_size; (void)ws_size;
  const float* v       = (const float*)d_in[0];
  const float* p0      = (const float*)d_in[1];
  const float* enc1_W  = (const float*)d_in[2];
  const float* enc1_b  = (const float*)d_in[3];
  const float* enc2_W  = (const float*)d_in[4];
  const float* enc2_b  = (const float*)d_in[5];
  const float* M_W     = (const float*)d_in[6];
  const float* M_b     = (const float*)d_in[7];
  const float* lstm_W  = (const float*)d_in[8];
  const float* lstm_U  = (const float*)d_in[9];
  const float* lstm_b  = (const float*)d_in[10];
  const float* dense_W = (const float*)d_in[11];
  const float* dense_b = (const float*)d_in[12];
  const float* dec_W   = (const float*)d_in[13];
  const float* dec_b   = (const float*)d_in[14];
  float* out = (float*)d_out;

  char* ws = (char*)d_ws;
  size_t off = 0;
  auto alloc = [&](size_t bytes) {
    char* p = ws + off;
    off += (bytes + 255) & ~(size_t)255;
    return p;
  };
  unsigned short* Ut    = (unsigned short*)alloc((size_t)N4 * NG * 2);   // 32 MB
  unsigned short* dWt   = (unsigned short*)alloc((size_t)NG * NG * 2);   // 8 MB
  unsigned short* decWt = (unsigned short*)alloc((size_t)NP * NG * 2);   // 2 MB
  unsigned short* encWt = (unsigned short*)alloc((size_t)2 * NG * NP * 2);
  unsigned short* p0b   = (unsigned short*)alloc((size_t)BB * NP * 2);
  float* W2r  = (float*)alloc((size_t)2 * N4 * 4);
  float* b2r  = (float*)alloc((size_t)N4 * 4);
  float* part = (float*)alloc((size_t)16 * 3 * N4 * 4);
  float* cfp  = (float*)alloc((size_t)BB * NG * 4);
  unsigned short* hb0 = (unsigned short*)alloc((size_t)BB * NG * 2);
  unsigned short* hs  = (unsigned short*)alloc((size_t)MR * NG * 2);     // 100 MB
  unsigned short* gc  = (unsigned short*)alloc((size_t)MR * NG * 2);     // 100 MB
  unsigned* bar = (unsigned*)alloc(1024);                                // barrier words

  dim3 blk(256), blk5(512);
  // barrier init (fresh every launch/replay)
  k_zero<<<dim3(1), blk, 0, stream>>>(bar);
  // weight conversion / transposes
  k_transpose_bf16<1><<<dim3(32, 128), blk, 0, stream>>>(lstm_U, Ut, NG, N4, 0);
  k_transpose_bf16<0><<<dim3(32, 32), blk, 0, stream>>>(dense_W, dWt, NG, NG, 0);
  k_transpose_bf16<0><<<dim3(32, 8), blk, 0, stream>>>(dec_W, decWt, NG, NP, 0);
  k_transpose_bf16<0><<<dim3(8, 32), blk, 0, stream>>>(enc1_W, encWt, NP, NG, 0);
  k_transpose_bf16<0><<<dim3(8, 32), blk, 0, stream>>>(enc2_W, encWt, NP, NG, NG);
  k_cvt<<<dim3(512), blk, 0, stream>>>(p0, p0b, BB * NP);
  // rank-2 collapse of input path
  k_prep_xw_part<<<dim3(32, 16), blk, 0, stream>>>(lstm_W, M_W, M_b, part);
  k_prep_xw_reduce<<<dim3(32), blk, 0, stream>>>(part, lstm_b, W2r, b2r);
  // initial state
  k_enc<<<dim3(4, 32), blk5, 0, stream>>>(p0b, encWt, enc1_b, enc2_b, hb0, cfp);
  // recurrence: one persistent kernel, 100 steps
  k_steps<<<dim3(NBLK), blk5, 0, stream>>>(Ut, v, W2r, b2r, cfp, hb0, hs, bar);
  // readout
  k_dense<<<dim3(3200), blk5, 0, stream>>>(hs, dWt, dense_b, gc);
  k_dec<<<dim3(200, 4), blk5, 0, stream>>>(gc, decWt, dec_b, out);
}

// Round 10
// 2041.968 us; speedup vs baseline: 1.9164x; 1.0234x over previous
//
#include <hip/hip_runtime.h>
#include <stdint.h>

#define DI __device__ __forceinline__

typedef short s16x8 __attribute__((ext_vector_type(8)));
typedef float f32x4 __attribute__((ext_vector_type(4)));

// ---- constants ----
#define NG   2048
#define NP   512
#define TT   100
#define BB   256
#define N4   8192   // 4*NG
#define MR   25600  // B*T
#define NBLK 256    // persistent grid size

DI unsigned short f32_to_bf16(float f) {
  union { float f; uint32_t u; } x; x.f = f;
  uint32_t r = x.u + 0x7fffu + ((x.u >> 16) & 1u);
  return (unsigned short)(r >> 16);
}

DI void async16(const void* g, void* l) {
  __builtin_amdgcn_global_load_lds((const __attribute__((address_space(1))) void*)g,
                                   (__attribute__((address_space(3))) void*)l,
                                   16, 0, 0);
}
DI void async4(const void* g, void* l) {
  __builtin_amdgcn_global_load_lds((const __attribute__((address_space(1))) void*)g,
                                   (__attribute__((address_space(3))) void*)l,
                                   4, 0, 0);
}

DI f32x4 mfma16(s16x8 a, s16x8 b, f32x4 c) {
  return __builtin_amdgcn_mfma_f32_16x16x32_bf16(a, b, c, 0, 0, 0);
}

__global__ __launch_bounds__(256) void k_zero(unsigned* p) {
  if (threadIdx.x < 160) p[threadIdx.x] = 0u;
}

// ---- software grid barrier: monotonic counters, RELAXED agent atomics ----
// (round-4/5 proven) No fences: cross-XCD data (hs) moves via write-through
// stores (drained by vmcnt(0) before arrival) and first-touch cached reads.
DI void grid_barrier2(unsigned* bar, int xcd, int t) {
  asm volatile("s_waitcnt vmcnt(0)" ::: "memory");  // h-stores globally visible
  __syncthreads();
  if (threadIdx.x == 0) {
    unsigned a = __hip_atomic_fetch_add(bar + xcd * 16, 1u,
                                        __ATOMIC_RELAXED, __HIP_MEMORY_SCOPE_AGENT);
    if (a + 1u == 32u * (unsigned)(t + 1)) {        // last block of this XCD
      unsigned g2 = __hip_atomic_fetch_add(bar + 128, 1u,
                                           __ATOMIC_RELAXED, __HIP_MEMORY_SCOPE_AGENT);
      if (g2 + 1u == 8u * (unsigned)(t + 1))        // last XCD
        __hip_atomic_store(bar + 144, (unsigned)(t + 1),
                           __ATOMIC_RELAXED, __HIP_MEMORY_SCOPE_AGENT);
    }
    while (__hip_atomic_load(bar + 144, __ATOMIC_RELAXED,
                             __HIP_MEMORY_SCOPE_AGENT) < (unsigned)(t + 1))
      __builtin_amdgcn_s_sleep(1);                  // fine poll: 64-cyc detect
  }
  __syncthreads();
}

// =====================================================================
// Pipelined bf16 MFMA core (non-persistent kernels) — unchanged.
// =====================================================================
template <int BM>
DI void gemm_core_p(const unsigned short* __restrict__ A, int lda, int m0,
                    const unsigned short* __restrict__ Bt, int ldb, int n0, int K,
                    unsigned short* sA, unsigned short* sB, f32x4* acc) {
  constexpr int FM = BM / 32;
  const int tid  = threadIdx.x;
  const int wave = tid >> 6;
  const int lane = tid & 63;
  const int quad = lane >> 4;
  const int lr   = lane & 15;
  const int wm   = wave >> 2;
  const int wn   = wave & 3;
  const int lr8  = lane >> 3;
  const int lc8  = lane & 7;
  const int scol = (lc8 ^ lr8) << 3;

  const int nkt = K >> 6;
  int buf = 0;

  auto stage = [&](int bsel, int k0) {
    unsigned short* dA = sA + bsel * (BM * 64);
    unsigned short* dB = sB + bsel * (128 * 64);
#pragma unroll
    for (int c = 0; c < BM / 64; ++c) {
      int rbase = wave * (BM / 8) + c * 8;
      const unsigned short* g = A + (size_t)(m0 + rbase + lr8) * lda + (k0 + scol);
      async16(g, dA + rbase * 64);
    }
#pragma unroll
    for (int c = 0; c < 2; ++c) {
      int rbase = wave * 16 + c * 8;
      const unsigned short* g = Bt + (size_t)(n0 + rbase + lr8) * ldb + (k0 + scol);
      async16(g, dB + rbase * 64);
    }
  };

  stage(0, 0);
  __syncthreads();
  for (int kt = 0; kt < nkt; ++kt) {
    if (kt + 1 < nkt) stage(buf ^ 1, (kt + 1) << 6);
    const char* cA = (const char*)(sA + buf * (BM * 64));
    const char* cB = (const char*)(sB + buf * (128 * 64));
#pragma unroll
    for (int ks = 0; ks < 2; ++ks) {
      s16x8 af[FM], bfr[2];
#pragma unroll
      for (int fm = 0; fm < FM; ++fm) {
        int row = wm * (BM / 2) + fm * 16 + lr;
        int off = row * 128 + ((ks * 64 + quad * 16) ^ ((row & 7) << 4));
        af[fm] = *(const s16x8*)(cA + off);
      }
#pragma unroll
      for (int fn = 0; fn < 2; ++fn) {
        int col = wn * 32 + fn * 16 + lr;
        int off = col * 128 + ((ks * 64 + quad * 16) ^ ((col & 7) << 4));
        bfr[fn] = *(const s16x8*)(cB + off);
      }
#pragma unroll
      for (int fm = 0; fm < FM; ++fm)
#pragma unroll
        for (int fn = 0; fn < 2; ++fn)
          acc[fm * 2 + fn] = mfma16(af[fm], bfr[fn], acc[fm * 2 + fn]);
    }
    __syncthreads();
    buf ^= 1;
  }
}

// =====================================================================
// Transpose + fp32->bf16. MODE 0: n = c + noff. MODE 1 (lstm_U gate/cell
// permutation): n = ((c&2047)>>4)*64 + ((c>>11)<<4) + (c&15)  — each
// 64-col group = 16 cells x 4 gates, so one lane's acc holds all 4 gates.
// =====================================================================
template <int MODE>
__global__ __launch_bounds__(256) void k_transpose_bf16(
    const float* __restrict__ src, unsigned short* __restrict__ dst,
    int R, int C, int noff) {
  __shared__ unsigned short tile[64][65];
  int tr0 = blockIdx.x * 64;
  int tc0 = blockIdx.y * 64;
  int tid = threadIdx.x;
#pragma unroll
  for (int i = 0; i < 16; ++i) {
    int idx = tid + i * 256;
    int r = idx >> 6, c = idx & 63;
    tile[r][c] = f32_to_bf16(src[(size_t)(tr0 + r) * C + (tc0 + c)]);
  }
  __syncthreads();
#pragma unroll
  for (int i = 0; i < 16; ++i) {
    int idx = tid + i * 256;
    int cc = idx >> 6, r = idx & 63;
    int c = tc0 + cc;
    int n = (MODE == 0) ? (c + noff)
                        : ((((c & 2047) >> 4) << 6) | (((c >> 11) & 3) << 4) | (c & 15));
    dst[(size_t)n * R + (tr0 + r)] = tile[r][cc];
  }
}

__global__ __launch_bounds__(256) void k_cvt(const float* __restrict__ src,
                                             unsigned short* __restrict__ dst, int n) {
  int i = blockIdx.x * 256 + threadIdx.x;
  if (i < n) dst[i] = f32_to_bf16(src[i]);
}

// ---- W2 = M_W @ lstm_W, bias2 = M_b @ lstm_W + lstm_b (gate-permuted) ----
__global__ __launch_bounds__(256) void k_prep_xw_part(
    const float* __restrict__ lstm_W, const float* __restrict__ M_W,
    const float* __restrict__ M_b, float* __restrict__ part) {
  int c = blockIdx.x * 256 + threadIdx.x;
  int kc = blockIdx.y;
  int k0 = kc * 128;
  float a0 = 0.f, a1 = 0.f, ab = 0.f;
  for (int k = k0; k < k0 + 128; ++k) {
    float w = lstm_W[(size_t)k * N4 + c];
    a0 += M_W[k] * w;
    a1 += M_W[NG + k] * w;
    ab += M_b[k] * w;
  }
  float* p = part + (size_t)kc * 3 * N4;
  p[c] = a0; p[N4 + c] = a1; p[2 * N4 + c] = ab;
}

__global__ __launch_bounds__(256) void k_prep_xw_reduce(
    const float* __restrict__ part, const float* __restrict__ lstm_b,
    float* __restrict__ W2r, float* __restrict__ b2r) {
  int c = blockIdx.x * 256 + threadIdx.x;
  float a0 = 0.f, a1 = 0.f, ab = 0.f;
  for (int kc = 0; kc < 16; ++kc) {
    const float* p = part + (size_t)kc * 3 * N4;
    a0 += p[c]; a1 += p[N4 + c]; ab += p[2 * N4 + c];
  }
  int n = (((c & 2047) >> 4) << 6) | (((c >> 11) & 3) << 4) | (c & 15);
  W2r[n] = a0; W2r[N4 + n] = a1; b2r[n] = ab + lstm_b[c];
}

// ---- encoders: [h0 | c0] = p0 @ [enc1_W ; enc2_W] packed as N=4096 ----
__global__ __launch_bounds__(512) void k_enc(
    const unsigned short* __restrict__ p0b, const unsigned short* __restrict__ encWt,
    const float* __restrict__ enc1_b, const float* __restrict__ enc2_b,
    unsigned short* __restrict__ hbf, float* __restrict__ cfp) {
  __shared__ __align__(16) unsigned short sA[2 * 64 * 64];
  __shared__ __align__(16) unsigned short sB[2 * 128 * 64];
  int m0 = blockIdx.x * 64, n0 = blockIdx.y * 128;
  const f32x4 vzero = {0.f, 0.f, 0.f, 0.f};
  f32x4 acc[4];
#pragma unroll
  for (int i = 0; i < 4; ++i) acc[i] = vzero;
  gemm_core_p<64>(p0b, NP, m0, encWt, NP, n0, NP, sA, sB, acc);

  const int tid = threadIdx.x, wave = tid >> 6, lane = tid & 63;
  const int quad = lane >> 4, lr = lane & 15, wm = wave >> 2, wn = wave & 3;
#pragma unroll
  for (int fm = 0; fm < 2; ++fm)
#pragma unroll
    for (int fn = 0; fn < 2; ++fn)
#pragma unroll
      for (int reg = 0; reg < 4; ++reg) {
        int grow = m0 + wm * 32 + fm * 16 + quad * 4 + reg;
        int gcol = n0 + wn * 32 + fn * 16 + lr;
        float val = acc[fm * 2 + fn][reg];
        if (gcol < NG)
          hbf[(size_t)grow * NG + gcol] = f32_to_bf16(val + enc1_b[gcol]);
        else
          cfp[(size_t)grow * NG + (gcol - NG)] = val + enc2_b[gcol - NG];
      }
}

// ---- persistent recurrence: all 100 LSTM steps ----
// 256 blocks (4 mt x 64 nt, XCD swizzle), 512 threads = 8 waves (2/SIMD).
// K-SPLIT waves: wave (kh, wm, wn) computes the ks=kh half of each BK=64
// phase for output tile (wm*32 rows, wn*64 cols). Ring-5 LDS, per-phase
// barrier + counted vmcnt (uniform 3 ops/wave/phase). Acc pair-merge:
// disjoint 128B block per lane + PER-ELEMENT index XOR (i ^ (lane&7)) —
// bijective within each block, 8 lanes cover all 32 banks, same involution
// on write and read. Register gate epilogue on kh=0 waves; tree barrier.
__global__ __launch_bounds__(512) void k_steps(
    const unsigned short* __restrict__ Ut,
    const float* __restrict__ vv, const float* __restrict__ W2r,
    const float* __restrict__ b2r, const float* __restrict__ cfp,
    const unsigned short* __restrict__ hb0,
    unsigned short* __restrict__ hs, unsigned* __restrict__ bar) {
  // A ring5 @0 (5x8KB), B ring5 @40960 (5x16KB), vvx @122880, vvy @123136,
  // htmp @123392 (4KB) -> 127488 B
  __shared__ __align__(16) char smem[127488];

  const int bid = blockIdx.x;           // XCD swizzle keeps Ut panel L2-resident
  const int xcd = bid & 7, sb = bid >> 3;
  const int mt = sb >> 3, nsub = sb & 7;
  const int nt = xcd * 8 + nsub;
  const int m0 = mt * 64, n0 = nt * 128;
  const int tid = threadIdx.x;
  const int w = tid >> 6, lane = tid & 63;
  const int kh = w >> 2;                // K-half this wave accumulates
  const int wq = w & 3;
  const int wm = wq >> 1, wn = wq & 1;
  const int quad = lane >> 4, lr = lane & 15;
  const int lr8 = lane >> 3, lc8 = lane & 7;
  const int scol = (lc8 ^ lr8) << 3;

  // ---- t-invariant state in registers (used by kh=0 waves) ----
  float w2x[4], w2y[4], bz[4];
#pragma unroll
  for (int g = 0; g < 4; ++g) {
    const int idx = n0 + wn * 64 + g * 16 + lr;
    w2x[g] = W2r[idx]; w2y[g] = W2r[N4 + idx]; bz[g] = b2r[idx];
  }
  const int cellg = nt * 32 + wn * 16 + lr;       // this thread's cell
  float cst[2][4];
#pragma unroll
  for (int fm = 0; fm < 2; ++fm)
#pragma unroll
    for (int reg = 0; reg < 4; ++reg) {
      const int r = wm * 32 + fm * 16 + quad * 4 + reg;
      cst[fm][reg] = cfp[(size_t)(m0 + r) * NG + cellg];
    }

  // merge: disjoint 128B block per lane; element swizzle via (i ^ l8)
  const int mrg = wq * 8192 + lane * 128;
  const int l8 = lane & 7;

  // staging split: per phase each wave does 1 A-op (rows 8w..8w+8) and
  // 2 B-ops (rows 16w..16w+16) -> uniform 3 vmem ops/wave/phase.
  const unsigned short* bwB = Ut + (size_t)(n0 + w * 16 + lr8) * NG + scol;
  auto stageB = [&](int slot, int k) {            // 2 ops
    char* dB = smem + 40960 + slot * 16384 + (w * 16) * 128;
    async16(bwB + k, dB);
    async16(bwB + (size_t)8 * NG + k, dB + 1024);
  };
  auto stageV = [&](int t) {                      // 2 ops (all waves duplicate)
    const float* gx = vv + ((size_t)(m0 + lane) * TT + t) * 2;
    async4(gx, smem + 122880);
    async4(gx + 1, smem + 123136);
  };

  f32x4 acc[8];
  auto computeS = [&](int slot) {
    const char* cA = smem + slot * 8192;
    const char* cB = smem + 40960 + slot * 16384;
    s16x8 af[2];
#pragma unroll
    for (int fm = 0; fm < 2; ++fm) {
      const int row = wm * 32 + fm * 16 + lr;
      af[fm] = *(const s16x8*)(cA + row * 128 + ((kh * 64 + quad * 16) ^ ((row & 7) << 4)));
    }
#pragma unroll
    for (int fn = 0; fn < 4; ++fn) {
      const int col = wn * 64 + fn * 16 + lr;
      s16x8 bf = *(const s16x8*)(cB + col * 128 + ((kh * 64 + quad * 16) ^ ((col & 7) << 4)));
#pragma unroll
      for (int fm = 0; fm < 2; ++fm)
        acc[fm * 4 + fn] = mfma16(af[fm], bf, acc[fm * 4 + fn]);
    }
  };

#define INC5(x) x = ((x) == 4) ? 0 : ((x) + 1)
#define PHASE(W)  asm volatile("s_waitcnt vmcnt(" #W ")\n\ts_barrier" ::: "memory"); \
                  computeS(cs); INC5(cs);

  asm volatile("s_waitcnt vmcnt(0)" ::: "memory");  // exact counting baseline
  int cs = 0;
  stageB(0, 0); stageB(1, 64); stageB(2, 128);      // t=0 B prefetch (6 ops)

  for (int t = 0; t < TT; ++t) {
    const unsigned short* hin = t ? hs + (size_t)(t - 1) * BB * NG : hb0;
    const unsigned short* awA = hin + (size_t)(m0 + w * 8 + lr8) * NG + scol;
    auto stageA = [&](int slot, int kt) {         // 1 op
      async16(awA + kt * 64, smem + slot * 8192 + (w * 8) * 128);
    };

    // entry: V (2 ops) + A into slots cs..cs+2 (1 op each)
    stageV(t);
    { int s1 = cs; stageA(s1, 0); INC5(s1); stageA(s1, 1); INC5(s1); stageA(s1, 2); }
    const f32x4 vzero = {0.f, 0.f, 0.f, 0.f};
#pragma unroll
    for (int i = 0; i < 8; ++i) acc[i] = vzero;

    int ss = cs; INC5(ss); INC5(ss); INC5(ss);    // stage slot = cs+3
    stageB(ss, 3 << 6); stageA(ss, 3); INC5(ss);
    PHASE(5)
    stageB(ss, 4 << 6); stageA(ss, 4); INC5(ss);
    PHASE(7)
    stageB(ss, 5 << 6); stageA(ss, 5); INC5(ss);
    PHASE(9)
    for (int p = 3; p <= 28; ++p) {
      stageB(ss, (p + 3) << 6); stageA(ss, p + 3); INC5(ss);
      PHASE(9)
    }
    PHASE(6)
    PHASE(3)
    PHASE(0)
    // next-step B prefetch into (new) cs..cs+2 (drained by grid barrier)
    if (t + 1 < TT) {
      int s2 = cs; stageB(s2, 0); INC5(s2); stageB(s2, 64); INC5(s2); stageB(s2, 128);
    }
    __syncthreads();                 // all compute done before LDS reuse

    // ---- acc pair-merge (kh=1 -> LDS -> kh=0), conflict-free & bijective ----
    if (kh) {
      f32x4* px = (f32x4*)(smem + mrg);
#pragma unroll
      for (int i = 0; i < 8; ++i) px[i ^ l8] = acc[i];
    }
    __syncthreads();
    if (!kh) {
      const f32x4* px = (const f32x4*)(smem + mrg);
#pragma unroll
      for (int i = 0; i < 8; ++i) acc[i] += px[i ^ l8];

      // ---- register gate epilogue ----
      const float* vx = (const float*)(smem + 122880);
      const float* vy = (const float*)(smem + 123136);
      unsigned short* htmp = (unsigned short*)(smem + 123392);
#pragma unroll
      for (int fm = 0; fm < 2; ++fm)
#pragma unroll
        for (int reg = 0; reg < 4; ++reg) {
          const int r = wm * 32 + fm * 16 + quad * 4 + reg;
          const float ax = vx[r], ay = vy[r];
          float zi = acc[fm * 4 + 0][reg] + ax * w2x[0] + ay * w2y[0] + bz[0];
          float zf = acc[fm * 4 + 1][reg] + ax * w2x[1] + ay * w2y[1] + bz[1];
          float zg = acc[fm * 4 + 2][reg] + ax * w2x[2] + ay * w2y[2] + bz[2];
          float zo = acc[fm * 4 + 3][reg] + ax * w2x[3] + ay * w2y[3] + bz[3];
          float i_ = 1.f / (1.f + __expf(-zi));
          float f_ = 1.f / (1.f + __expf(-zf));
          float g_ = fmaxf(zg, 0.f);
          float o_ = 1.f / (1.f + __expf(-zo));
          float cn = f_ * cst[fm][reg] + i_ * g_;
          cst[fm][reg] = cn;
          htmp[r * 32 + wn * 16 + lr] = f32_to_bf16(o_ * fmaxf(cn, 0.f));
        }
    }
    __syncthreads();
    // coalesced 4B write-through h stores into hs[t] (all 8 waves)
    {
      const unsigned* hw = (const unsigned*)(smem + 123392);
#pragma unroll
      for (int p = 0; p < 2; ++p) {
        const int q = tid + p * 512;       // 0..1023 uints (64 rows x 16)
        const int r = q >> 4, cq = q & 15;
        unsigned* hp = (unsigned*)(hs + ((size_t)t * BB + m0 + r) * NG) + (nt * 16 + cq);
        __hip_atomic_store(hp, hw[q], __ATOMIC_RELAXED, __HIP_MEMORY_SCOPE_AGENT);
      }
    }
    if (t + 1 < TT) grid_barrier2(bar, xcd, t);   // drains everything (vmcnt 0)
  }
#undef PHASE
#undef INC5
}

// ---- g_cells = relu(hs @ dense_W + dense_b) -> bf16 ----
__global__ __launch_bounds__(512) void k_dense(
    const unsigned short* __restrict__ hs, const unsigned short* __restrict__ dWt,
    const float* __restrict__ dense_b, unsigned short* __restrict__ gc) {
  __shared__ __align__(16) unsigned short sA[2 * 128 * 64];
  __shared__ __align__(16) unsigned short sB[2 * 128 * 64];
  int bid = blockIdx.x;
  int mt = bid >> 4;
  int r4 = bid & 15;
  int nt = ((r4 & 7) << 1) | (r4 >> 3);   // fixed nt pair per XCD
  int m0 = mt * 128, n0 = nt * 128;
  const f32x4 vzero = {0.f, 0.f, 0.f, 0.f};
  f32x4 acc[8];
#pragma unroll
  for (int i = 0; i < 8; ++i) acc[i] = vzero;
  gemm_core_p<128>(hs, NG, m0, dWt, NG, n0, NG, sA, sB, acc);

  const int tid = threadIdx.x, wave = tid >> 6, lane = tid & 63;
  const int quad = lane >> 4, lr = lane & 15, wm = wave >> 2, wn = wave & 3;
#pragma unroll
  for (int fm = 0; fm < 4; ++fm)
#pragma unroll
    for (int fn = 0; fn < 2; ++fn)
#pragma unroll
      for (int reg = 0; reg < 4; ++reg) {
        int grow = m0 + wm * 64 + fm * 16 + quad * 4 + reg;
        int gcol = n0 + wn * 32 + fn * 16 + lr;
        float val = fmaxf(acc[fm * 2 + fn][reg] + dense_b[gcol], 0.f);
        gc[(size_t)grow * NG + gcol] = f32_to_bf16(val);
      }
}

// ---- place_preds = g_cells @ dec_W + dec_b (fp32 out, [B][T][Np]) ----
__global__ __launch_bounds__(512) void k_dec(
    const unsigned short* __restrict__ gc, const unsigned short* __restrict__ decWt,
    const float* __restrict__ dec_b, float* __restrict__ out) {
  __shared__ __align__(16) unsigned short sA[2 * 128 * 64];
  __shared__ __align__(16) unsigned short sB[2 * 128 * 64];
  int m0 = blockIdx.x * 128, n0 = blockIdx.y * 128;
  const f32x4 vzero = {0.f, 0.f, 0.f, 0.f};
  f32x4 acc[8];
#pragma unroll
  for (int i = 0; i < 8; ++i) acc[i] = vzero;
  gemm_core_p<128>(gc, NG, m0, decWt, NG, n0, NG, sA, sB, acc);

  const int tid = threadIdx.x, wave = tid >> 6, lane = tid & 63;
  const int quad = lane >> 4, lr = lane & 15, wm = wave >> 2, wn = wave & 3;
#pragma unroll
  for (int fm = 0; fm < 4; ++fm)
#pragma unroll
    for (int fn = 0; fn < 2; ++fn)
#pragma unroll
      for (int reg = 0; reg < 4; ++reg) {
        int grow = m0 + wm * 64 + fm * 16 + quad * 4 + reg;   // t*256+b
        int gcol = n0 + wn * 32 + fn * 16 + lr;               // 0..511
        int tt = grow >> 8, b = grow & 255;
        out[((size_t)b * TT + tt) * NP + gcol] = acc[fm * 2 + fn][reg] + dec_b[gcol];
      }
}

// =====================================================================
extern "C" void kernel_launch(void* const* d_in, const int* in_sizes, int n_in,
                              void* d_out, int out_size, void* d_ws, size_t ws_size,
                              hipStream_t stream) {
  (void)in_sizes; (void)n_in; (void)out_size; (void)ws_size;
  const float* v       = (const float*)d_in[0];
  const float* p0      = (const float*)d_in[1];
  const float* enc1_W  = (const float*)d_in[2];
  const float* enc1_b  = (const float*)d_in[3];
  const float* enc2_W  = (const float*)d_in[4];
  const float* enc2_b  = (const float*)d_in[5];
  const float* M_W     = (const float*)d_in[6];
  const float* M_b     = (const float*)d_in[7];
  const float* lstm_W  = (const float*)d_in[8];
  const float* lstm_U  = (const float*)d_in[9];
  const float* lstm_b  = (const float*)d_in[10];
  const float* dense_W = (const float*)d_in[11];
  const float* dense_b = (const float*)d_in[12];
  const float* dec_W   = (const float*)d_in[13];
  const float* dec_b   = (const float*)d_in[14];
  float* out = (float*)d_out;

  char* ws = (char*)d_ws;
  size_t off = 0;
  auto alloc = [&](size_t bytes) {
    char* p = ws + off;
    off += (bytes + 255) & ~(size_t)255;
    return p;
  };
  unsigned short* Ut    = (unsigned short*)alloc((size_t)N4 * NG * 2);   // 32 MB
  unsigned short* dWt   = (unsigned short*)alloc((size_t)NG * NG * 2);   // 8 MB
  unsigned short* decWt = (unsigned short*)alloc((size_t)NP * NG * 2);   // 2 MB
  unsigned short* encWt = (unsigned short*)alloc((size_t)2 * NG * NP * 2);
  unsigned short* p0b   = (unsigned short*)alloc((size_t)BB * NP * 2);
  float* W2r  = (float*)alloc((size_t)2 * N4 * 4);
  float* b2r  = (float*)alloc((size_t)N4 * 4);
  float* part = (float*)alloc((size_t)16 * 3 * N4 * 4);
  float* cfp  = (float*)alloc((size_t)BB * NG * 4);
  unsigned short* hb0 = (unsigned short*)alloc((size_t)BB * NG * 2);
  unsigned short* hs  = (unsigned short*)alloc((size_t)MR * NG * 2);     // 100 MB
  unsigned short* gc  = (unsigned short*)alloc((size_t)MR * NG * 2);     // 100 MB
  unsigned* bar = (unsigned*)alloc(1024);                                // barrier words

  dim3 blk(256), blk5(512);
  // barrier init (fresh every launch/replay)
  k_zero<<<dim3(1), blk, 0, stream>>>(bar);
  // weight conversion / transposes
  k_transpose_bf16<1><<<dim3(32, 128), blk, 0, stream>>>(lstm_U, Ut, NG, N4, 0);
  k_transpose_bf16<0><<<dim3(32, 32), blk, 0, stream>>>(dense_W, dWt, NG, NG, 0);
  k_transpose_bf16<0><<<dim3(32, 8), blk, 0, stream>>>(dec_W, decWt, NG, NP, 0);
  k_transpose_bf16<0><<<dim3(8, 32), blk, 0, stream>>>(enc1_W, encWt, NP, NG, 0);
  k_transpose_bf16<0><<<dim3(8, 32), blk, 0, stream>>>(enc2_W, encWt, NP, NG, NG);
  k_cvt<<<dim3(512), blk, 0, stream>>>(p0, p0b, BB * NP);
  // rank-2 collapse of input path
  k_prep_xw_part<<<dim3(32, 16), blk, 0, stream>>>(lstm_W, M_W, M_b, part);
  k_prep_xw_reduce<<<dim3(32), blk, 0, stream>>>(part, lstm_b, W2r, b2r);
  // initial state
  k_enc<<<dim3(4, 32), blk5, 0, stream>>>(p0b, encWt, enc1_b, enc2_b, hb0, cfp);
  // recurrence: one persistent kernel, 100 steps
  k_steps<<<dim3(NBLK), blk5, 0, stream>>>(Ut, v, W2r, b2r, cfp, hb0, hs, bar);
  // readout
  k_dense<<<dim3(3200), blk5, 0, stream>>>(hs, dWt, dense_b, gc);
  k_dec<<<dim3(200, 4), blk5, 0, stream>>>(gc, decWt, dec_b, out);
}